// Round 1
// baseline (521.779 us; speedup 1.0000x reference)
//
#include <hip/hip_runtime.h>
#include <stdint.h>

// Problem constants (from reference): B=32, S=512, P=8, K=256, D=64
#define NGROUPS (32 * 512 * 8)   // B*S*P = 131072 argmax groups
#define WAVES_PER_BLOCK 4

#define ROTL(x, r) (((x) << (r)) | ((x) >> (32 - (r))))

// threefry2x32 with key (0, 42) [= jax.random.key(42)], counter (0, n),
// partitionable 32-bit fold: return out0 ^ out1.
__device__ __forceinline__ unsigned tf42_bits(unsigned n) {
    const unsigned K0 = 0u;
    const unsigned K1 = 42u;
    const unsigned K2 = 0x1BD11BDAu ^ 0u ^ 42u;  // 0x1BD11BF0
    unsigned x0 = 0u + K0;   // hi counter + ks[0]
    unsigned x1 = n + K1;    // lo counter + ks[1]

#define TF_ROUND(r) x0 += x1; x1 = ROTL(x1, r); x1 ^= x0;
    // group 1: rotations {13,15,26,6}
    TF_ROUND(13) TF_ROUND(15) TF_ROUND(26) TF_ROUND(6)
    x0 += K1; x1 += K2 + 1u;
    // group 2: rotations {17,29,16,24}
    TF_ROUND(17) TF_ROUND(29) TF_ROUND(16) TF_ROUND(24)
    x0 += K2; x1 += K0 + 2u;
    // group 3
    TF_ROUND(13) TF_ROUND(15) TF_ROUND(26) TF_ROUND(6)
    x0 += K0; x1 += K1 + 3u;
    // group 4
    TF_ROUND(17) TF_ROUND(29) TF_ROUND(16) TF_ROUND(24)
    x0 += K1; x1 += K2 + 4u;
    // group 5
    TF_ROUND(13) TF_ROUND(15) TF_ROUND(26) TF_ROUND(6)
    x0 += K2; x1 += K0 + 5u;
#undef TF_ROUND
    return x0 ^ x1;
}

// Exact jax.random.uniform(minval=tiny, maxval=1) + gumbel transform:
// f = ((bits>>9)|0x3f800000).f32 - 1; u = f==0 ? tiny : f; g = -log(-log(u))
__device__ __forceinline__ float gumbel_from_bits(unsigned bits) {
    float f = __uint_as_float((bits >> 9) | 0x3f800000u) - 1.0f;
    float u = (f == 0.0f) ? 1.17549435e-38f : f;
    return -__ocml_log_f32(-__ocml_log_f32(u));
}

extern "C" __device__ float __ocml_log_f32(float);

__global__ __launch_bounds__(256) void se_gumbel_kernel(
    const int* __restrict__ inputs,      // [B,S] int32
    const float* __restrict__ pmap,      // [N_CAT, P, K] = [50000, 8, 256]
    const float* __restrict__ symbols,   // [K, D] = [256, 64]
    const float* __restrict__ tau,       // [1]
    float* __restrict__ out)             // [B, S, P*D]
{
    const int lane = threadIdx.x & 63;
    const int wave = threadIdx.x >> 6;
    const int group = blockIdx.x * WAVES_PER_BLOCK + wave;  // = bs*8 + p
    const int p  = group & 7;
    const int bs = group >> 3;

    const int cat = inputs[bs];
    const float tv = tau[0];

    // Coalesced: lane i loads energies k = 4i..4i+3 (16B per lane, 1KB/wave)
    const float4 e4 = *reinterpret_cast<const float4*>(
        pmap + (size_t)cat * 2048 + (size_t)p * 256 + (size_t)lane * 4);
    const float ev[4] = {e4.x, e4.y, e4.z, e4.w};

    // Element linear index into the [B,S,P,K] noise tensor
    const unsigned nbase = ((unsigned)group << 8) + (unsigned)(lane * 4);

    float best = -__builtin_inff();
    int bestk = 0;
    #pragma unroll
    for (int j = 0; j < 4; ++j) {
        const unsigned bits = tf42_bits(nbase + j);
        float f = __uint_as_float((bits >> 9) | 0x3f800000u) - 1.0f;
        float u = (f == 0.0f) ? 1.17549435e-38f : f;
        float g = -logf(-logf(u));           // precise ocml logf, fp32
        float x = (ev[j] + g) / tv;          // tau division (tau==1 -> exact)
        // strict > keeps the FIRST max within the lane (k ascending)
        if (x > best) { best = x; bestk = lane * 4 + j; }
    }

    // Wave argmax reduction with first-index tie-break (jnp.argmax semantics)
    #pragma unroll
    for (int off = 32; off > 0; off >>= 1) {
        float ov = __shfl_down(best, off, 64);
        int   ok = __shfl_down(bestk, off, 64);
        if (ov > best || (ov == best && ok < bestk)) { best = ov; bestk = ok; }
    }
    bestk = __shfl(bestk, 0, 64);

    // weights == one_hot(bestk) exactly (non-argmax: (0-s)+s == 0; argmax: 1±1ulp)
    // => out row = symbols[bestk, :], coalesced 64-float write
    out[(size_t)group * 64 + lane] = symbols[(size_t)bestk * 64 + lane];
}

extern "C" void kernel_launch(void* const* d_in, const int* in_sizes, int n_in,
                              void* d_out, int out_size, void* d_ws, size_t ws_size,
                              hipStream_t stream) {
    const int*   inputs  = (const int*)d_in[0];
    const float* pmap    = (const float*)d_in[1];
    const float* symbols = (const float*)d_in[2];
    const float* tau     = (const float*)d_in[3];
    float* out = (float*)d_out;

    const int n_blocks = NGROUPS / WAVES_PER_BLOCK;  // 32768
    hipLaunchKernelGGL(se_gumbel_kernel, dim3(n_blocks), dim3(256), 0, stream,
                       inputs, pmap, symbols, tau, out);
}

// Round 2
// 513.953 us; speedup vs baseline: 1.0152x; 1.0152x over previous
//
#include <hip/hip_runtime.h>
#include <stdint.h>

// Problem constants (from reference): B=32, S=512, P=8, K=256, D=64
#define NGROUPS (32 * 512 * 8)   // B*S*P = 131072 argmax groups
#define WAVES_PER_BLOCK 4

#define ROTL(x, r) (((x) << (r)) | ((x) >> (32 - (r))))

// threefry2x32, key (0,42) [= jax.random.key(42)], counter (0,n),
// partitionable 32-bit fold: out0 ^ out1. Bit-exact vs JAX (absmax=0 in R1).
__device__ __forceinline__ unsigned tf42_bits(unsigned n) {
    const unsigned K0 = 0u;
    const unsigned K1 = 42u;
    const unsigned K2 = 0x1BD11BDAu ^ 0u ^ 42u;  // 0x1BD11BF0
    unsigned x0 = 0u + K0;
    unsigned x1 = n + K1;
#define TF_ROUND(r) x0 += x1; x1 = ROTL(x1, r); x1 ^= x0;
    TF_ROUND(13) TF_ROUND(15) TF_ROUND(26) TF_ROUND(6)
    x0 += K1; x1 += K2 + 1u;
    TF_ROUND(17) TF_ROUND(29) TF_ROUND(16) TF_ROUND(24)
    x0 += K2; x1 += K0 + 2u;
    TF_ROUND(13) TF_ROUND(15) TF_ROUND(26) TF_ROUND(6)
    x0 += K0; x1 += K1 + 3u;
    TF_ROUND(17) TF_ROUND(29) TF_ROUND(16) TF_ROUND(24)
    x0 += K1; x1 += K2 + 4u;
    TF_ROUND(13) TF_ROUND(15) TF_ROUND(26) TF_ROUND(6)
    x0 += K2; x1 += K0 + 5u;
#undef TF_ROUND
    return x0 ^ x1;
}

__device__ __forceinline__ float u_from_bits(unsigned bits) {
    // exact jax.random.uniform(tiny, 1) reduction
    float f = __uint_as_float((bits >> 9) | 0x3f800000u) - 1.0f;
    return (f == 0.0f) ? 1.17549435e-38f : f;
}

// Precise path — instruction-identical to the verified round-1 kernel
// (ocml logf, <=1ulp; matched np argmax exactly, absmax=0).
__device__ __forceinline__ float precise_g(unsigned bits) {
    float u = u_from_bits(bits);
    return -logf(-logf(u));
}

#define NLN2 (-0.693147180559945f)
#define BAND 0.015625f            /* 2^-6: > 2x the fast-path error bound */
#define L2U_NEAR1 (-1.220703125e-4f)  /* -2^-13: hw-log2 abs-err danger zone */

__global__ __launch_bounds__(256) void se_gumbel_kernel(
    const int* __restrict__ inputs,      // [B,S] int32
    const float* __restrict__ pmap,      // [50000, 8, 256] f32
    const float* __restrict__ symbols,   // [256, 64] f32
    const float* __restrict__ tau,       // [1]
    float* __restrict__ out)             // [B, S, P*D]
{
    const int lane = threadIdx.x & 63;
    const int wave = threadIdx.x >> 6;
    const int group = blockIdx.x * WAVES_PER_BLOCK + wave;  // = bs*8 + p
    const int p  = group & 7;
    const int bs = group >> 3;

    const int cat = inputs[bs];
    // tau > 0: argmax((e+g)/tau) == argmax(e+g); tau < 0 flips to argmin.
    const float rs = (tau[0] > 0.0f) ? 1.0f : -1.0f;

    // Coalesced gather: lane i loads energies k = 4i..4i+3 (1 KB/wave)
    const float4 e4 = *reinterpret_cast<const float4*>(
        pmap + (size_t)cat * 2048 + (size_t)p * 256 + (size_t)lane * 4);
    const float ev[4] = {e4.x, e4.y, e4.z, e4.w};

    const unsigned nbase = ((unsigned)group << 8) + (unsigned)(lane * 4);

    // ---- Pass 1: fast approximate scores (hw v_log_f32 = log2) ----
    unsigned bits[4];
    float xt[4];
    float lmax = -__builtin_inff();
    #pragma unroll
    for (int j = 0; j < 4; ++j) {
        bits[j] = tf42_bits(nbase + j);
        float u = u_from_bits(bits[j]);
        float l2u = __builtin_amdgcn_logf(u);   // v_log_f32: log2(u), < 0
        float x;
        if (l2u > L2U_NEAR1) {
            // u within 2^-13 of 1: hw-log2 abs error can dominate -> precise
            x = rs * (ev[j] + precise_g(bits[j]));
        } else {
            float L = l2u * NLN2;                         // -ln(u) > 0
            float g = __builtin_amdgcn_logf(L) * NLN2;    // -ln(L)
            x = rs * (ev[j] + g);
        }
        xt[j] = x;
        lmax = fmaxf(lmax, x);
    }

    // ---- Wave max of approximate scores ----
    #pragma unroll
    for (int off = 32; off > 0; off >>= 1)
        lmax = fmaxf(lmax, __shfl_down(lmax, off, 64));
    const float T = __shfl(lmax, 0, 64) - BAND;

    // ---- Pass 2: precise re-eval of band candidates only (usually 1/wave) ----
    float best = -__builtin_inff();
    int bestk = 0x7fffffff;
    #pragma unroll
    for (int j = 0; j < 4; ++j) {
        if (xt[j] >= T) {
            float px = rs * (ev[j] + precise_g(bits[j]));
            int k = lane * 4 + j;
            if (px > best || (px == best && k < bestk)) { best = px; bestk = k; }
        }
    }

    // Wave argmax with first-index tie-break (jnp.argmax semantics)
    #pragma unroll
    for (int off = 32; off > 0; off >>= 1) {
        float ov = __shfl_down(best, off, 64);
        int   ok = __shfl_down(bestk, off, 64);
        if (ov > best || (ov == best && ok < bestk)) { best = ov; bestk = ok; }
    }
    bestk = __shfl(bestk, 0, 64);

    // weights == one_hot(bestk) numerically => out row = symbols[bestk, :]
    out[(size_t)group * 64 + lane] = symbols[(size_t)bestk * 64 + lane];
}

extern "C" void kernel_launch(void* const* d_in, const int* in_sizes, int n_in,
                              void* d_out, int out_size, void* d_ws, size_t ws_size,
                              hipStream_t stream) {
    const int*   inputs  = (const int*)d_in[0];
    const float* pmap    = (const float*)d_in[1];
    const float* symbols = (const float*)d_in[2];
    const float* tau     = (const float*)d_in[3];
    float* out = (float*)d_out;

    const int n_blocks = NGROUPS / WAVES_PER_BLOCK;  // 32768
    hipLaunchKernelGGL(se_gumbel_kernel, dim3(n_blocks), dim3(256), 0, stream,
                       inputs, pmap, symbols, tau, out);
}